// Round 6
// baseline (282.386 us; speedup 1.0000x reference)
//
#include <hip/hip_runtime.h>

typedef __bf16 bf16x8 __attribute__((ext_vector_type(8)));
typedef float f32x4 __attribute__((ext_vector_type(4)));

__device__ __forceinline__ void gload16(const void* g, void* l) {
    __builtin_amdgcn_global_load_lds(
        (const __attribute__((address_space(1))) unsigned int*)g,
        (__attribute__((address_space(3))) unsigned int*)l, 16, 0, 0);
}

// ---- phase 1a: x fp32 -> bf16 ----
__global__ void k_convert_x(const float* __restrict__ x, __bf16* __restrict__ xb, size_t n) {
    size_t i = ((size_t)blockIdx.x * blockDim.x + threadIdx.x) * 8;
    if (i >= n) return;
    const float4 a = *(const float4*)(x + i);
    const float4 b = *(const float4*)(x + i + 4);
    bf16x8 v;
    v[0] = (__bf16)a.x; v[1] = (__bf16)a.y; v[2] = (__bf16)a.z; v[3] = (__bf16)a.w;
    v[4] = (__bf16)b.x; v[5] = (__bf16)b.y; v[6] = (__bf16)b.z; v[7] = (__bf16)b.w;
    *(bf16x8*)(xb + i) = v;
}

// ---- phase 1b: W int4-in-int32 -> dequantized bf16 ----
__global__ void k_dequant_w(const int* __restrict__ wq, const float* __restrict__ scale,
                            const float* __restrict__ zp, __bf16* __restrict__ wb,
                            int K, int GS, int NG) {
    size_t i = ((size_t)blockIdx.x * blockDim.x + threadIdx.x) * 8;
    int o = (int)(i / K);
    int k = (int)(i % K);
    int g = k / GS;
    float s = scale[(size_t)o * NG + g];
    float z = zp[(size_t)o * NG + g];
    const int4 q0 = *(const int4*)(wq + i);
    const int4 q1 = *(const int4*)(wq + i + 4);
    bf16x8 v;
    v[0] = (__bf16)(((float)q0.x - z) * s); v[1] = (__bf16)(((float)q0.y - z) * s);
    v[2] = (__bf16)(((float)q0.z - z) * s); v[3] = (__bf16)(((float)q0.w - z) * s);
    v[4] = (__bf16)(((float)q1.x - z) * s); v[5] = (__bf16)(((float)q1.y - z) * s);
    v[6] = (__bf16)(((float)q1.z - z) * s); v[7] = (__bf16)(((float)q1.w - z) * s);
    *(bf16x8*)(wb + i) = v;
}

// =====================================================================
// 256x256 deep-pipelined GEMM, BK=32, 4 LDS buffers, read-ahead frags,
// ONE barrier per K-tile, K-loop unrolled x4 (compile-time buffers).
// vmcnt ledger: stages for tile tt issued at tile tt-3 (guard tt<NT);
// steady state: vmcnt(4) at tile top leaves only prev tile's 4 loads in
// flight. Tail: tile NT-2's boundary needs vmcnt(0) (its predecessor
// issued no stages, so vmcnt(4) would not force the needed drain).
// lgkm ledger: 8 outstanding at tile top; lgkm(4) before m0-3 (drains
// a03/B of t), lgkm(8) before m4-7 (drains a47 of t).
// Swizzle (T2): LDS[row][j] = G[row][j ^ ((row>>1)&3)], read chunk
// hi ^ ((lr>>1)&3) -> conflict-free ds_read_b128 (verified: conflicts=0).
// =====================================================================
#define BKg 32
#define TILEB 32768     // (256+256)*32*2 bytes per K-tile buffer
#define ATILEB 16384    // A region size within buffer

__global__ __launch_bounds__(512, 2) void k_gemm256(
    const __bf16* __restrict__ A, const __bf16* __restrict__ B,
    const float* __restrict__ bias, float* __restrict__ C,
    int M, int N, int K)
{
    __shared__ __align__(16) char lds[4 * TILEB];   // 128 KiB
    const int tid = threadIdx.x;
    const int w = tid >> 6, lane = tid & 63;
    const int wm = w >> 2, wn = w & 3;              // 2 (M) x 4 (N) waves
    const int lr = lane & 15, hi = lane >> 4;
    const int NT = K / BKg;

    // bijective XCD-aware block swizzle (m204)
    const int nbx = N / 256;
    const int nwg = nbx * (M / 256);
    const int bid = (int)blockIdx.x;
    const int q = nwg >> 3, r = nwg & 7;
    const int xcd = bid & 7, loc = bid >> 3;
    const int swz = (xcd < r ? xcd * (q + 1) : r * (q + 1) + (xcd - r) * q) + loc;
    const int m0 = (swz / nbx) * 256;
    const int n0 = (swz % nbx) * 256;

    // staging source offsets (pre-swizzled global source, linear LDS dest)
    int aO[2], bO[2];
#pragma unroll
    for (int L = 0; L < 2; ++L) {
        int c = L * 512 + tid;
        int row = c >> 2, ch = (c & 3) ^ ((c >> 3) & 3);
        aO[L] = (m0 + row) * K + ch * 8;
        bO[L] = (n0 + row) * K + ch * 8;
    }
    const int dstOff0 = (w * 64) * 16;          // wave-uniform LDS dest
    const int dstOff1 = (512 + w * 64) * 16;

    // fragment read byte offsets (swizzled read: chunk = hi ^ ((row>>1)&3))
    const int chR = (hi ^ ((lr >> 1) & 3)) * 16;
    const int aRd = (wm * 128 + lr) * 64 + chR;
    const int bRd = ATILEB + (wn * 64 + lr) * 64 + chR;

#define RD_A(dst, BUF, m) dst = *(const bf16x8*)(lds + (BUF) * TILEB + aRd + (m) * 1024)
#define RD_B(dst, BUF, n) dst = *(const bf16x8*)(lds + (BUF) * TILEB + bRd + (n) * 1024)
#define VMW(n) asm volatile("s_waitcnt vmcnt(" #n ")" ::: "memory")
#define LKW(n) asm volatile("s_waitcnt lgkmcnt(" #n ")" ::: "memory")

    f32x4 acc[8][4] = {};
    bf16x8 a03[4], a47[4], b0[4], b1[4];

    // prologue: stage tiles 0,1,2 into bufs 0,1,2 ; publish tile0 ; read frags
    gload16(A + aO[0],            lds + 0 * TILEB + dstOff0);
    gload16(A + aO[1],            lds + 0 * TILEB + dstOff1);
    gload16(B + bO[0],            lds + 0 * TILEB + ATILEB + dstOff0);
    gload16(B + bO[1],            lds + 0 * TILEB + ATILEB + dstOff1);
    gload16(A + aO[0] + BKg,      lds + 1 * TILEB + dstOff0);
    gload16(A + aO[1] + BKg,      lds + 1 * TILEB + dstOff1);
    gload16(B + bO[0] + BKg,      lds + 1 * TILEB + ATILEB + dstOff0);
    gload16(B + bO[1] + BKg,      lds + 1 * TILEB + ATILEB + dstOff1);
    gload16(A + aO[0] + 2 * BKg,  lds + 2 * TILEB + dstOff0);
    gload16(A + aO[1] + 2 * BKg,  lds + 2 * TILEB + dstOff1);
    gload16(B + bO[0] + 2 * BKg,  lds + 2 * TILEB + ATILEB + dstOff0);
    gload16(B + bO[1] + 2 * BKg,  lds + 2 * TILEB + ATILEB + dstOff1);
    VMW(8);
    __builtin_amdgcn_s_barrier();
    RD_A(a03[0], 0, 0); RD_A(a03[1], 0, 1); RD_A(a03[2], 0, 2); RD_A(a03[3], 0, 3);
    RD_B(b0[0], 0, 0);  RD_B(b0[1], 0, 1);  RD_B(b0[2], 0, 2);  RD_B(b0[3], 0, 3);
    // invariant: 8 lgkm outstanding at each tile top

    const __bf16* Ab3 = A + 3 * BKg;   // uniform staging base (tile t+3)
    const __bf16* Bb3 = B + 3 * BKg;

#define ITERU(t, I, BT, BT1, BT3, BCUR, BNXT, VN)                            \
do {                                                                         \
    VMW(VN);                                                                 \
    __builtin_amdgcn_s_barrier();                                            \
    if ((t) + (I) + 3 < NT) {                                                \
        gload16(Ab3 + aO[0] + (I) * BKg, lds + (BT3) * TILEB + dstOff0);     \
        gload16(Ab3 + aO[1] + (I) * BKg, lds + (BT3) * TILEB + dstOff1);     \
    }                                                                        \
    RD_A(a47[0], BT, 4); RD_A(a47[1], BT, 5);                                \
    RD_A(a47[2], BT, 6); RD_A(a47[3], BT, 7);                                \
    LKW(4);                                                                  \
    __builtin_amdgcn_sched_barrier(0);                                       \
    __builtin_amdgcn_s_setprio(1);                                           \
    _Pragma("unroll")                                                        \
    for (int m_ = 0; m_ < 4; ++m_)                                           \
        _Pragma("unroll")                                                    \
        for (int n_ = 0; n_ < 4; ++n_)                                       \
            acc[m_][n_] = __builtin_amdgcn_mfma_f32_16x16x32_bf16(           \
                a03[m_], BCUR[n_], acc[m_][n_], 0, 0, 0);                    \
    __builtin_amdgcn_s_setprio(0);                                           \
    if ((t) + (I) + 3 < NT) {                                                \
        gload16(Bb3 + bO[0] + (I) * BKg,                                     \
                lds + (BT3) * TILEB + ATILEB + dstOff0);                     \
        gload16(Bb3 + bO[1] + (I) * BKg,                                     \
                lds + (BT3) * TILEB + ATILEB + dstOff1);                     \
    }                                                                        \
    if ((t) + (I) + 1 < NT) {                                                \
        RD_A(a03[0], BT1, 0); RD_A(a03[1], BT1, 1);                          \
        RD_A(a03[2], BT1, 2); RD_A(a03[3], BT1, 3);                          \
        RD_B(BNXT[0], BT1, 0); RD_B(BNXT[1], BT1, 1);                        \
        RD_B(BNXT[2], BT1, 2); RD_B(BNXT[3], BT1, 3);                        \
        LKW(8);                                                              \
    } else {                                                                 \
        LKW(0);                                                              \
    }                                                                        \
    __builtin_amdgcn_sched_barrier(0);                                       \
    __builtin_amdgcn_s_setprio(1);                                           \
    _Pragma("unroll")                                                        \
    for (int m_ = 0; m_ < 4; ++m_)                                           \
        _Pragma("unroll")                                                    \
        for (int n_ = 0; n_ < 4; ++n_)                                       \
            acc[m_ + 4][n_] = __builtin_amdgcn_mfma_f32_16x16x32_bf16(       \
                a47[m_], BCUR[n_], acc[m_ + 4][n_], 0, 0, 0);                \
    __builtin_amdgcn_s_setprio(0);                                           \
} while (0)

    int t = 0;
    for (; t < NT - 4; t += 4) {
        ITERU(t, 0, 0, 1, 3, b0, b1, 4);
        ITERU(t, 1, 1, 2, 0, b1, b0, 4);
        ITERU(t, 2, 2, 3, 1, b0, b1, 4);
        ITERU(t, 3, 3, 0, 2, b1, b0, 4);
        Ab3 += 4 * BKg;
        Bb3 += 4 * BKg;
    }
    // peeled last group (t == NT-4): vmcnt(0) at tops of tiles NT-2, NT-1
    ITERU(t, 0, 0, 1, 3, b0, b1, 4);
    ITERU(t, 1, 1, 2, 0, b1, b0, 4);
    ITERU(t, 2, 2, 3, 1, b0, b1, 0);
    ITERU(t, 3, 3, 0, 2, b1, b0, 0);

    // epilogue: C = acc + bias (C/D layout: col=lane&15, row=(lane>>4)*4+reg)
#pragma unroll
    for (int n_ = 0; n_ < 4; ++n_) {
        const int col = n0 + wn * 64 + n_ * 16 + lr;
        const float bv = bias[col];
#pragma unroll
        for (int m_ = 0; m_ < 8; ++m_) {
            const size_t rbase = (size_t)(m0 + wm * 128 + m_ * 16 + hi * 4) * N + col;
            C[rbase]                 = acc[m_][n_][0] + bv;
            C[rbase + N]             = acc[m_][n_][1] + bv;
            C[rbase + 2 * (size_t)N] = acc[m_][n_][2] + bv;
            C[rbase + 3 * (size_t)N] = acc[m_][n_][3] + bv;
        }
    }
#undef ITERU
#undef RD_A
#undef RD_B
#undef VMW
#undef LKW
}

// ---- fallback 128x128 GEMM (round-1 verified) ----
template <int MODE>
__global__ __launch_bounds__(256, 2) void k_gemm(
    const __bf16* __restrict__ Ab, const float* __restrict__ Af,
    const __bf16* __restrict__ Bb, const int* __restrict__ Bq,
    const float* __restrict__ scale, const float* __restrict__ zp,
    const float* __restrict__ bias, float* __restrict__ C,
    int M, int N, int K, int NG, int GS)
{
    __shared__ __align__(16) __bf16 As[128 * 32];
    __shared__ __align__(16) __bf16 Bs[128 * 32];

    const int tid  = threadIdx.x;
    const int w    = tid >> 6;
    const int lane = tid & 63;
    const int wm   = w >> 1, wn = w & 1;
    const int m0   = blockIdx.y * 128, n0 = blockIdx.x * 128;
    const int lr   = lane & 15;
    const int lc   = lane >> 4;

    f32x4 acc[4][4] = {};

    for (int kk = 0; kk < K; kk += 32) {
        if constexpr (MODE == 0) {
#pragma unroll
            for (int i = 0; i < 2; i++) {
                int c = i * 256 + tid;
                const __bf16* g = Ab + (size_t)(m0 + (c >> 2)) * K + kk + (c & 3) * 8;
                gload16(g, (char*)As + (i * 256 + w * 64) * 16);
            }
        } else {
            int row = tid >> 1, half = tid & 1;
            const float* g = Af + (size_t)(m0 + row) * K + kk + half * 16;
            float4 f0 = *(const float4*)g;
            float4 f1 = *(const float4*)(g + 4);
            float4 f2 = *(const float4*)(g + 8);
            float4 f3 = *(const float4*)(g + 12);
            bf16x8 v0, v1;
            v0[0] = (__bf16)f0.x; v0[1] = (__bf16)f0.y; v0[2] = (__bf16)f0.z; v0[3] = (__bf16)f0.w;
            v0[4] = (__bf16)f1.x; v0[5] = (__bf16)f1.y; v0[6] = (__bf16)f1.z; v0[7] = (__bf16)f1.w;
            v1[0] = (__bf16)f2.x; v1[1] = (__bf16)f2.y; v1[2] = (__bf16)f2.z; v1[3] = (__bf16)f2.w;
            v1[4] = (__bf16)f3.x; v1[5] = (__bf16)f3.y; v1[6] = (__bf16)f3.z; v1[7] = (__bf16)f3.w;
            *(bf16x8*)(As + row * 32 + half * 16)     = v0;
            *(bf16x8*)(As + row * 32 + half * 16 + 8) = v1;
        }
        if constexpr (MODE <= 1) {
#pragma unroll
            for (int i = 0; i < 2; i++) {
                int c = i * 256 + tid;
                const __bf16* g = Bb + (size_t)(n0 + (c >> 2)) * K + kk + (c & 3) * 8;
                gload16(g, (char*)Bs + (i * 256 + w * 64) * 16);
            }
        } else {
            int row = tid >> 1, half = tid & 1;
            int o = n0 + row;
            int kbase = kk + half * 16;
            int g = kbase / GS;
            float s = scale[(size_t)o * NG + g];
            float z = zp[(size_t)o * NG + g];
            const int* qp = Bq + (size_t)o * K + kbase;
            int4 q0 = *(const int4*)qp;
            int4 q1 = *(const int4*)(qp + 4);
            int4 q2 = *(const int4*)(qp + 8);
            int4 q3 = *(const int4*)(qp + 12);
            bf16x8 v0, v1;
            v0[0] = (__bf16)(((float)q0.x - z) * s); v0[1] = (__bf16)(((float)q0.y - z) * s);
            v0[2] = (__bf16)(((float)q0.z - z) * s); v0[3] = (__bf16)(((float)q0.w - z) * s);
            v0[4] = (__bf16)(((float)q1.x - z) * s); v0[5] = (__bf16)(((float)q1.y - z) * s);
            v0[6] = (__bf16)(((float)q1.z - z) * s); v0[7] = (__bf16)(((float)q1.w - z) * s);
            v1[0] = (__bf16)(((float)q2.x - z) * s); v1[1] = (__bf16)(((float)q2.y - z) * s);
            v1[2] = (__bf16)(((float)q2.z - z) * s); v1[3] = (__bf16)(((float)q2.w - z) * s);
            v1[4] = (__bf16)(((float)q3.x - z) * s); v1[5] = (__bf16)(((float)q3.y - z) * s);
            v1[6] = (__bf16)(((float)q3.z - z) * s); v1[7] = (__bf16)(((float)q3.w - z) * s);
            *(bf16x8*)(Bs + row * 32 + half * 16)     = v0;
            *(bf16x8*)(Bs + row * 32 + half * 16 + 8) = v1;
        }

        __syncthreads();

        bf16x8 af[4], bfm[4];
#pragma unroll
        for (int a = 0; a < 4; a++)
            af[a] = *(const bf16x8*)(As + (wm * 64 + a * 16 + lr) * 32 + lc * 8);
#pragma unroll
        for (int b = 0; b < 4; b++)
            bfm[b] = *(const bf16x8*)(Bs + (wn * 64 + b * 16 + lr) * 32 + lc * 8);
#pragma unroll
        for (int a = 0; a < 4; a++)
#pragma unroll
            for (int b = 0; b < 4; b++)
                acc[a][b] = __builtin_amdgcn_mfma_f32_16x16x32_bf16(af[a], bfm[b], acc[a][b], 0, 0, 0);

        __syncthreads();
    }

#pragma unroll
    for (int b = 0; b < 4; b++) {
        int col = n0 + wn * 64 + b * 16 + lr;
        float bv = bias[col];
#pragma unroll
        for (int a = 0; a < 4; a++) {
            int rbase = m0 + wm * 64 + a * 16 + lc * 4;
#pragma unroll
            for (int r = 0; r < 4; r++)
                C[(size_t)(rbase + r) * N + col] = acc[a][b][r] + bv;
        }
    }
}

extern "C" void kernel_launch(void* const* d_in, const int* in_sizes, int n_in,
                              void* d_out, int out_size, void* d_ws, size_t ws_size,
                              hipStream_t stream) {
    const float* x     = (const float*)d_in[0];
    const int*   wq    = (const int*)d_in[1];
    const float* scale = (const float*)d_in[2];
    const float* zp    = (const float*)d_in[3];
    const float* bias  = (const float*)d_in[4];
    float* out = (float*)d_out;

    const int    N  = in_sizes[4];
    const long   K  = in_sizes[1] / N;
    const long   M  = in_sizes[0] / K;
    const int    NG = in_sizes[2] / N;
    const int    GS = (int)(K / NG);

    const size_t wbytes = (size_t)N * K * sizeof(__bf16);
    const size_t xbytes = (size_t)M * K * sizeof(__bf16);

    char* ws = (char*)d_ws;
    __bf16* wb = (__bf16*)ws;
    __bf16* xb = (__bf16*)(ws + wbytes);

    const bool big = (M % 256 == 0) && (N % 256 == 0) && (K % 128 == 0) && (K / 32 >= 8);

    if (ws_size >= wbytes + xbytes) {
        size_t nx = (size_t)M * K;
        size_t nw = (size_t)N * K;
        k_convert_x<<<(unsigned)((nx / 8 + 255) / 256), 256, 0, stream>>>(x, xb, nx);
        k_dequant_w<<<(unsigned)((nw / 8 + 255) / 256), 256, 0, stream>>>(wq, scale, zp, wb, (int)K, GS, NG);
        if (big) {
            unsigned nwg = (unsigned)((M / 256) * (N / 256));
            k_gemm256<<<nwg, 512, 0, stream>>>(xb, wb, bias, out, (int)M, N, (int)K);
        } else {
            dim3 grid((unsigned)(N / 128), (unsigned)(M / 128)), blk(256);
            k_gemm<0><<<grid, blk, 0, stream>>>(xb, nullptr, wb, nullptr, scale, zp, bias, out,
                                                (int)M, N, (int)K, NG, GS);
        }
    } else if (ws_size >= wbytes) {
        size_t nw = (size_t)N * K;
        dim3 grid((unsigned)(N / 128), (unsigned)(M / 128)), blk(256);
        k_dequant_w<<<(unsigned)((nw / 8 + 255) / 256), 256, 0, stream>>>(wq, scale, zp, wb, (int)K, GS, NG);
        k_gemm<1><<<grid, blk, 0, stream>>>(nullptr, x, wb, nullptr, scale, zp, bias, out,
                                            (int)M, N, (int)K, NG, GS);
    } else {
        dim3 grid((unsigned)(N / 128), (unsigned)(M / 128)), blk(256);
        k_gemm<2><<<grid, blk, 0, stream>>>(nullptr, x, nullptr, wq, scale, zp, bias, out,
                                            (int)M, N, (int)K, NG, GS);
    }
}

// Round 7
// 243.642 us; speedup vs baseline: 1.1590x; 1.1590x over previous
//
#include <hip/hip_runtime.h>

typedef __bf16 bf16x8 __attribute__((ext_vector_type(8)));
typedef float f32x4 __attribute__((ext_vector_type(4)));

__device__ __forceinline__ void gload16(const void* g, void* l) {
    __builtin_amdgcn_global_load_lds(
        (const __attribute__((address_space(1))) unsigned int*)g,
        (__attribute__((address_space(3))) unsigned int*)l, 16, 0, 0);
}

// ---- phase 1a: x fp32 -> bf16 ----
__global__ void k_convert_x(const float* __restrict__ x, __bf16* __restrict__ xb, size_t n) {
    size_t i = ((size_t)blockIdx.x * blockDim.x + threadIdx.x) * 8;
    if (i >= n) return;
    const float4 a = *(const float4*)(x + i);
    const float4 b = *(const float4*)(x + i + 4);
    bf16x8 v;
    v[0] = (__bf16)a.x; v[1] = (__bf16)a.y; v[2] = (__bf16)a.z; v[3] = (__bf16)a.w;
    v[4] = (__bf16)b.x; v[5] = (__bf16)b.y; v[6] = (__bf16)b.z; v[7] = (__bf16)b.w;
    *(bf16x8*)(xb + i) = v;
}

// ---- phase 1b: W int4-in-int32 -> dequantized bf16 ----
__global__ void k_dequant_w(const int* __restrict__ wq, const float* __restrict__ scale,
                            const float* __restrict__ zp, __bf16* __restrict__ wb,
                            int K, int GS, int NG) {
    size_t i = ((size_t)blockIdx.x * blockDim.x + threadIdx.x) * 8;
    int o = (int)(i / K);
    int k = (int)(i % K);
    int g = k / GS;
    float s = scale[(size_t)o * NG + g];
    float z = zp[(size_t)o * NG + g];
    const int4 q0 = *(const int4*)(wq + i);
    const int4 q1 = *(const int4*)(wq + i + 4);
    bf16x8 v;
    v[0] = (__bf16)(((float)q0.x - z) * s); v[1] = (__bf16)(((float)q0.y - z) * s);
    v[2] = (__bf16)(((float)q0.z - z) * s); v[3] = (__bf16)(((float)q0.w - z) * s);
    v[4] = (__bf16)(((float)q1.x - z) * s); v[5] = (__bf16)(((float)q1.y - z) * s);
    v[6] = (__bf16)(((float)q1.z - z) * s); v[7] = (__bf16)(((float)q1.w - z) * s);
    *(bf16x8*)(wb + i) = v;
}

// =====================================================================
// 256x256 deep-pipelined GEMM, BK=32, 4 LDS buffers, read-ahead frags,
// ONE barrier per K-tile. ROUND-5 STRUCTURE verbatim (verified 125us,
// conflicts=0, absmax ok) with ONE delta: K-loop unrolled x4 so buffer
// indices are compile-time literals -> ds_read addresses fold to
// loop-invariant base + immediate (kills per-tile LDS address VALU).
// Branchless wrap staging (cselect), sched_barrier walls, setprio,
// vmcnt(4)/lgkm(4/8) ledger all UNCHANGED from round 5.
// Ledger recap:
//   vmcnt(4) @ tile top: 12 outstanding (tiles t,t+1,t+2 stages) ->
//   drains 8 oldest = tile t's + tile t+1's loads. Wrap stages at the
//   tail keep counts exact; wrapped data never read.
//   lgkm: 8 outstanding at tile top; LKW(4) before m0-3, LKW(8) before
//   m4-7; tail uses LKW(0).
// Swizzle (T2): LDS[row][j] = G[row][j ^ ((row>>1)&3)], read chunk
// hi ^ ((lr>>1)&3) -> conflict-free ds_read_b128 (verified: conflicts=0).
// =====================================================================
#define BKg 32
#define TILEB 32768     // (256+256)*32*2 bytes per K-tile buffer
#define ATILEB 16384    // A region size within buffer

__global__ __launch_bounds__(512, 2) void k_gemm256(
    const __bf16* __restrict__ A, const __bf16* __restrict__ B,
    const float* __restrict__ bias, float* __restrict__ C,
    int M, int N, int K)
{
    __shared__ __align__(16) char lds[4 * TILEB];   // 128 KiB
    const int tid = threadIdx.x;
    const int w = tid >> 6, lane = tid & 63;
    const int wm = w >> 2, wn = w & 3;              // 2 (M) x 4 (N) waves
    const int lr = lane & 15, hi = lane >> 4;
    const int NT = K / BKg;

    // bijective XCD-aware block swizzle (m204)
    const int nbx = N / 256;
    const int nwg = nbx * (M / 256);
    const int bid = (int)blockIdx.x;
    const int q = nwg >> 3, r = nwg & 7;
    const int xcd = bid & 7, loc = bid >> 3;
    const int swz = (xcd < r ? xcd * (q + 1) : r * (q + 1) + (xcd - r) * q) + loc;
    const int m0 = (swz / nbx) * 256;
    const int n0 = (swz % nbx) * 256;

    // staging source offsets (pre-swizzled global source, linear LDS dest)
    size_t aOff[2], bOff[2];
#pragma unroll
    for (int L = 0; L < 2; ++L) {
        int c = L * 512 + tid;
        int row = c >> 2, ch = (c & 3) ^ ((c >> 3) & 3);
        aOff[L] = (size_t)(m0 + row) * K + ch * 8;
        bOff[L] = (size_t)(n0 + row) * K + ch * 8;
    }
    int dstOff[2];
#pragma unroll
    for (int L = 0; L < 2; ++L) dstOff[L] = (L * 512 + w * 64) * 16;  // wave-uniform

    // fragment read byte offsets (swizzled read: chunk = hi ^ ((row>>1)&3))
    const int chR = (hi ^ ((lr >> 1) & 3)) * 16;
    const int aRd = (wm * 128 + lr) * 64 + chR;
    const int bRd = ATILEB + (wn * 64 + lr) * 64 + chR;

#define STAGE_A(tt, BUF) do {                                              \
    const int kk_ = (tt) * BKg;                                            \
    gload16(A + aOff[0] + kk_, lds + (BUF) * TILEB + dstOff[0]);           \
    gload16(A + aOff[1] + kk_, lds + (BUF) * TILEB + dstOff[1]);           \
} while (0)
#define STAGE_B(tt, BUF) do {                                              \
    const int kk_ = (tt) * BKg;                                            \
    gload16(B + bOff[0] + kk_, lds + (BUF) * TILEB + ATILEB + dstOff[0]);  \
    gload16(B + bOff[1] + kk_, lds + (BUF) * TILEB + ATILEB + dstOff[1]);  \
} while (0)
#define RD_A(dst, BUF, m) dst = *(const bf16x8*)(lds + (BUF) * TILEB + aRd + (m) * 1024)
#define RD_B(dst, BUF, n) dst = *(const bf16x8*)(lds + (BUF) * TILEB + bRd + (n) * 1024)
#define VMW(n) asm volatile("s_waitcnt vmcnt(" #n ")" ::: "memory")
#define LKW(n) asm volatile("s_waitcnt lgkmcnt(" #n ")" ::: "memory")

    f32x4 acc[8][4] = {};
    bf16x8 a03[4], a47[4], b0[4], b1[4];

    // prologue: stage tiles 0,1,2 into bufs 0,1,2 ; publish tile0 ; read frags
    STAGE_A(0, 0); STAGE_B(0, 0);
    STAGE_A(1, 1); STAGE_B(1, 1);
    STAGE_A(2, 2); STAGE_B(2, 2);
    VMW(8);
    __builtin_amdgcn_s_barrier();
    RD_A(a03[0], 0, 0); RD_A(a03[1], 0, 1); RD_A(a03[2], 0, 2); RD_A(a03[3], 0, 3);
    RD_B(b0[0], 0, 0);  RD_B(b0[1], 0, 1);  RD_B(b0[2], 0, 2);  RD_B(b0[3], 0, 3);
    // invariant: 8 lgkm outstanding at each tile top

#define ITERC(t, I, BT, BT1, BT3, BCUR, BNXT)                                \
do {                                                                         \
    int t3 = (t) + (I) + 3; if (t3 >= NT) t3 -= NT;                          \
    /* ---- tile boundary: ONE vmcnt + ONE barrier ---- */                   \
    VMW(4);                                                                  \
    __builtin_amdgcn_s_barrier();                                            \
    /* ---- ph0: stage A(t+3); read a47(t); MFMA m0-3(t) ---- */             \
    STAGE_A(t3, BT3);                                                        \
    RD_A(a47[0], BT, 4); RD_A(a47[1], BT, 5);                                \
    RD_A(a47[2], BT, 6); RD_A(a47[3], BT, 7);                                \
    LKW(4);                                                                  \
    __builtin_amdgcn_sched_barrier(0);                                       \
    __builtin_amdgcn_s_setprio(1);                                           \
    _Pragma("unroll")                                                        \
    for (int m_ = 0; m_ < 4; ++m_)                                           \
        _Pragma("unroll")                                                    \
        for (int n_ = 0; n_ < 4; ++n_)                                       \
            acc[m_][n_] = __builtin_amdgcn_mfma_f32_16x16x32_bf16(           \
                a03[m_], BCUR[n_], acc[m_][n_], 0, 0, 0);                    \
    __builtin_amdgcn_s_setprio(0);                                           \
    __builtin_amdgcn_sched_barrier(0);                                       \
    /* ---- ph1: stage B(t+3); read a03/B(t+1); MFMA m4-7(t) ---- */         \
    STAGE_B(t3, BT3);                                                        \
    if ((t) + (I) + 1 < NT) {                                                \
        RD_A(a03[0], BT1, 0); RD_A(a03[1], BT1, 1);                          \
        RD_A(a03[2], BT1, 2); RD_A(a03[3], BT1, 3);                          \
        RD_B(BNXT[0], BT1, 0); RD_B(BNXT[1], BT1, 1);                        \
        RD_B(BNXT[2], BT1, 2); RD_B(BNXT[3], BT1, 3);                        \
        LKW(8);                                                              \
    } else {                                                                 \
        LKW(0);                                                              \
    }                                                                        \
    __builtin_amdgcn_sched_barrier(0);                                       \
    __builtin_amdgcn_s_setprio(1);                                           \
    _Pragma("unroll")                                                        \
    for (int m_ = 0; m_ < 4; ++m_)                                           \
        _Pragma("unroll")                                                    \
        for (int n_ = 0; n_ < 4; ++n_)                                       \
            acc[m_ + 4][n_] = __builtin_amdgcn_mfma_f32_16x16x32_bf16(       \
                a47[m_], BCUR[n_], acc[m_ + 4][n_], 0, 0, 0);                \
    __builtin_amdgcn_s_setprio(0);                                           \
    __builtin_amdgcn_sched_barrier(0);                                       \
} while (0)

    for (int t = 0; t + 4 <= NT; t += 4) {
        ITERC(t, 0, 0, 1, 3, b0, b1);
        ITERC(t, 1, 1, 2, 0, b1, b0);
        ITERC(t, 2, 2, 3, 1, b0, b1);
        ITERC(t, 3, 3, 0, 2, b1, b0);
    }

    // epilogue: C = acc + bias (C/D layout: col=lane&15, row=(lane>>4)*4+reg)
#pragma unroll
    for (int n_ = 0; n_ < 4; ++n_) {
        const int col = n0 + wn * 64 + n_ * 16 + lr;
        const float bv = bias[col];
#pragma unroll
        for (int m_ = 0; m_ < 8; ++m_) {
            const size_t rbase = (size_t)(m0 + wm * 128 + m_ * 16 + hi * 4) * N + col;
            C[rbase]                 = acc[m_][n_][0] + bv;
            C[rbase + N]             = acc[m_][n_][1] + bv;
            C[rbase + 2 * (size_t)N] = acc[m_][n_][2] + bv;
            C[rbase + 3 * (size_t)N] = acc[m_][n_][3] + bv;
        }
    }
#undef ITERC
#undef STAGE_A
#undef STAGE_B
#undef RD_A
#undef RD_B
#undef VMW
#undef LKW
}

// ---- fallback 128x128 GEMM (round-1 verified) ----
template <int MODE>
__global__ __launch_bounds__(256, 2) void k_gemm(
    const __bf16* __restrict__ Ab, const float* __restrict__ Af,
    const __bf16* __restrict__ Bb, const int* __restrict__ Bq,
    const float* __restrict__ scale, const float* __restrict__ zp,
    const float* __restrict__ bias, float* __restrict__ C,
    int M, int N, int K, int NG, int GS)
{
    __shared__ __align__(16) __bf16 As[128 * 32];
    __shared__ __align__(16) __bf16 Bs[128 * 32];

    const int tid  = threadIdx.x;
    const int w    = tid >> 6;
    const int lane = tid & 63;
    const int wm   = w >> 1, wn = w & 1;
    const int m0   = blockIdx.y * 128, n0 = blockIdx.x * 128;
    const int lr   = lane & 15;
    const int lc   = lane >> 4;

    f32x4 acc[4][4] = {};

    for (int kk = 0; kk < K; kk += 32) {
        if constexpr (MODE == 0) {
#pragma unroll
            for (int i = 0; i < 2; i++) {
                int c = i * 256 + tid;
                const __bf16* g = Ab + (size_t)(m0 + (c >> 2)) * K + kk + (c & 3) * 8;
                gload16(g, (char*)As + (i * 256 + w * 64) * 16);
            }
        } else {
            int row = tid >> 1, half = tid & 1;
            const float* g = Af + (size_t)(m0 + row) * K + kk + half * 16;
            float4 f0 = *(const float4*)g;
            float4 f1 = *(const float4*)(g + 4);
            float4 f2 = *(const float4*)(g + 8);
            float4 f3 = *(const float4*)(g + 12);
            bf16x8 v0, v1;
            v0[0] = (__bf16)f0.x; v0[1] = (__bf16)f0.y; v0[2] = (__bf16)f0.z; v0[3] = (__bf16)f0.w;
            v0[4] = (__bf16)f1.x; v0[5] = (__bf16)f1.y; v0[6] = (__bf16)f1.z; v0[7] = (__bf16)f1.w;
            v1[0] = (__bf16)f2.x; v1[1] = (__bf16)f2.y; v1[2] = (__bf16)f2.z; v1[3] = (__bf16)f2.w;
            v1[4] = (__bf16)f3.x; v1[5] = (__bf16)f3.y; v1[6] = (__bf16)f3.z; v1[7] = (__bf16)f3.w;
            *(bf16x8*)(As + row * 32 + half * 16)     = v0;
            *(bf16x8*)(As + row * 32 + half * 16 + 8) = v1;
        }
        if constexpr (MODE <= 1) {
#pragma unroll
            for (int i = 0; i < 2; i++) {
                int c = i * 256 + tid;
                const __bf16* g = Bb + (size_t)(n0 + (c >> 2)) * K + kk + (c & 3) * 8;
                gload16(g, (char*)Bs + (i * 256 + w * 64) * 16);
            }
        } else {
            int row = tid >> 1, half = tid & 1;
            int o = n0 + row;
            int kbase = kk + half * 16;
            int g = kbase / GS;
            float s = scale[(size_t)o * NG + g];
            float z = zp[(size_t)o * NG + g];
            const int* qp = Bq + (size_t)o * K + kbase;
            int4 q0 = *(const int4*)qp;
            int4 q1 = *(const int4*)(qp + 4);
            int4 q2 = *(const int4*)(qp + 8);
            int4 q3 = *(const int4*)(qp + 12);
            bf16x8 v0, v1;
            v0[0] = (__bf16)(((float)q0.x - z) * s); v0[1] = (__bf16)(((float)q0.y - z) * s);
            v0[2] = (__bf16)(((float)q0.z - z) * s); v0[3] = (__bf16)(((float)q0.w - z) * s);
            v0[4] = (__bf16)(((float)q1.x - z) * s); v0[5] = (__bf16)(((float)q1.y - z) * s);
            v0[6] = (__bf16)(((float)q1.z - z) * s); v0[7] = (__bf16)(((float)q1.w - z) * s);
            v1[0] = (__bf16)(((float)q2.x - z) * s); v1[1] = (__bf16)(((float)q2.y - z) * s);
            v1[2] = (__bf16)(((float)q2.z - z) * s); v1[3] = (__bf16)(((float)q2.w - z) * s);
            v1[4] = (__bf16)(((float)q3.x - z) * s); v1[5] = (__bf16)(((float)q3.y - z) * s);
            v1[6] = (__bf16)(((float)q3.z - z) * s); v1[7] = (__bf16)(((float)q3.w - z) * s);
            *(bf16x8*)(Bs + row * 32 + half * 16)     = v0;
            *(bf16x8*)(Bs + row * 32 + half * 16 + 8) = v1;
        }

        __syncthreads();

        bf16x8 af[4], bfm[4];
#pragma unroll
        for (int a = 0; a < 4; a++)
            af[a] = *(const bf16x8*)(As + (wm * 64 + a * 16 + lr) * 32 + lc * 8);
#pragma unroll
        for (int b = 0; b < 4; b++)
            bfm[b] = *(const bf16x8*)(Bs + (wn * 64 + b * 16 + lr) * 32 + lc * 8);
#pragma unroll
        for (int a = 0; a < 4; a++)
#pragma unroll
            for (int b = 0; b < 4; b++)
                acc[a][b] = __builtin_amdgcn_mfma_f32_16x16x32_bf16(af[a], bfm[b], acc[a][b], 0, 0, 0);

        __syncthreads();
    }

#pragma unroll
    for (int b = 0; b < 4; b++) {
        int col = n0 + wn * 64 + b * 16 + lr;
        float bv = bias[col];
#pragma unroll
        for (int a = 0; a < 4; a++) {
            int rbase = m0 + wm * 64 + a * 16 + lc * 4;
#pragma unroll
            for (int r = 0; r < 4; r++)
                C[(size_t)(rbase + r) * N + col] = acc[a][b][r] + bv;
        }
    }
}

extern "C" void kernel_launch(void* const* d_in, const int* in_sizes, int n_in,
                              void* d_out, int out_size, void* d_ws, size_t ws_size,
                              hipStream_t stream) {
    const float* x     = (const float*)d_in[0];
    const int*   wq    = (const int*)d_in[1];
    const float* scale = (const float*)d_in[2];
    const float* zp    = (const float*)d_in[3];
    const float* bias  = (const float*)d_in[4];
    float* out = (float*)d_out;

    const int    N  = in_sizes[4];
    const long   K  = in_sizes[1] / N;
    const long   M  = in_sizes[0] / K;
    const int    NG = in_sizes[2] / N;
    const int    GS = (int)(K / NG);

    const size_t wbytes = (size_t)N * K * sizeof(__bf16);
    const size_t xbytes = (size_t)M * K * sizeof(__bf16);

    char* ws = (char*)d_ws;
    __bf16* wb = (__bf16*)ws;
    __bf16* xb = (__bf16*)(ws + wbytes);

    const bool big = (M % 256 == 0) && (N % 256 == 0) && (K % 128 == 0) && (K / 32 >= 8);

    if (ws_size >= wbytes + xbytes) {
        size_t nx = (size_t)M * K;
        size_t nw = (size_t)N * K;
        k_convert_x<<<(unsigned)((nx / 8 + 255) / 256), 256, 0, stream>>>(x, xb, nx);
        k_dequant_w<<<(unsigned)((nw / 8 + 255) / 256), 256, 0, stream>>>(wq, scale, zp, wb, (int)K, GS, NG);
        if (big) {
            unsigned nwg = (unsigned)((M / 256) * (N / 256));
            k_gemm256<<<nwg, 512, 0, stream>>>(xb, wb, bias, out, (int)M, N, (int)K);
        } else {
            dim3 grid((unsigned)(N / 128), (unsigned)(M / 128)), blk(256);
            k_gemm<0><<<grid, blk, 0, stream>>>(xb, nullptr, wb, nullptr, scale, zp, bias, out,
                                                (int)M, N, (int)K, NG, GS);
        }
    } else if (ws_size >= wbytes) {
        size_t nw = (size_t)N * K;
        dim3 grid((unsigned)(N / 128), (unsigned)(M / 128)), blk(256);
        k_dequant_w<<<(unsigned)((nw / 8 + 255) / 256), 256, 0, stream>>>(wq, scale, zp, wb, (int)K, GS, NG);
        k_gemm<1><<<grid, blk, 0, stream>>>(nullptr, x, wb, nullptr, scale, zp, bias, out,
                                            (int)M, N, (int)K, NG, GS);
    } else {
        dim3 grid((unsigned)(N / 128), (unsigned)(M / 128)), blk(256);
        k_gemm<2><<<grid, blk, 0, stream>>>(nullptr, x, nullptr, wq, scale, zp, bias, out,
                                            (int)M, N, (int)K, NG, GS);
    }
}

// Round 8
// 143.854 us; speedup vs baseline: 1.9630x; 1.6937x over previous
//
#include <hip/hip_runtime.h>

typedef __bf16 bf16x8 __attribute__((ext_vector_type(8)));
typedef float f32x4 __attribute__((ext_vector_type(4)));

__device__ __forceinline__ void gload16(const void* g, void* l) {
    __builtin_amdgcn_global_load_lds(
        (const __attribute__((address_space(1))) unsigned int*)g,
        (__attribute__((address_space(3))) unsigned int*)l, 16, 0, 0);
}

// ---- fused pre-pass: x fp32->bf16 (blocks [0,nxb)), W dequant (blocks [nxb,...)) ----
__global__ void k_prep(const float* __restrict__ x, __bf16* __restrict__ xb, size_t nx,
                       const int* __restrict__ wq, const float* __restrict__ scale,
                       const float* __restrict__ zp, __bf16* __restrict__ wb,
                       int K, int GS, int NG, int nxb) {
    const int bid = (int)blockIdx.x;
    if (bid < nxb) {
        size_t i = ((size_t)bid * blockDim.x + threadIdx.x) * 8;
        if (i >= nx) return;
        const float4 a = *(const float4*)(x + i);
        const float4 b = *(const float4*)(x + i + 4);
        bf16x8 v;
        v[0] = (__bf16)a.x; v[1] = (__bf16)a.y; v[2] = (__bf16)a.z; v[3] = (__bf16)a.w;
        v[4] = (__bf16)b.x; v[5] = (__bf16)b.y; v[6] = (__bf16)b.z; v[7] = (__bf16)b.w;
        *(bf16x8*)(xb + i) = v;
    } else {
        size_t i = ((size_t)(bid - nxb) * blockDim.x + threadIdx.x) * 8;
        int o = (int)(i / K);
        int k = (int)(i % K);
        int g = k / GS;
        float s = scale[(size_t)o * NG + g];
        float z = zp[(size_t)o * NG + g];
        const int4 q0 = *(const int4*)(wq + i);
        const int4 q1 = *(const int4*)(wq + i + 4);
        bf16x8 v;
        v[0] = (__bf16)(((float)q0.x - z) * s); v[1] = (__bf16)(((float)q0.y - z) * s);
        v[2] = (__bf16)(((float)q0.z - z) * s); v[3] = (__bf16)(((float)q0.w - z) * s);
        v[4] = (__bf16)(((float)q1.x - z) * s); v[5] = (__bf16)(((float)q1.y - z) * s);
        v[6] = (__bf16)(((float)q1.z - z) * s); v[7] = (__bf16)(((float)q1.w - z) * s);
        *(bf16x8*)(wb + i) = v;
    }
}

// ---- standalone dequant (fallback MODE 1 path) ----
__global__ void k_dequant_w(const int* __restrict__ wq, const float* __restrict__ scale,
                            const float* __restrict__ zp, __bf16* __restrict__ wb,
                            int K, int GS, int NG) {
    size_t i = ((size_t)blockIdx.x * blockDim.x + threadIdx.x) * 8;
    int o = (int)(i / K);
    int k = (int)(i % K);
    int g = k / GS;
    float s = scale[(size_t)o * NG + g];
    float z = zp[(size_t)o * NG + g];
    const int4 q0 = *(const int4*)(wq + i);
    const int4 q1 = *(const int4*)(wq + i + 4);
    bf16x8 v;
    v[0] = (__bf16)(((float)q0.x - z) * s); v[1] = (__bf16)(((float)q0.y - z) * s);
    v[2] = (__bf16)(((float)q0.z - z) * s); v[3] = (__bf16)(((float)q0.w - z) * s);
    v[4] = (__bf16)(((float)q1.x - z) * s); v[5] = (__bf16)(((float)q1.y - z) * s);
    v[6] = (__bf16)(((float)q1.z - z) * s); v[7] = (__bf16)(((float)q1.w - z) * s);
    *(bf16x8*)(wb + i) = v;
}

// =====================================================================
// 256x256 deep-pipelined GEMM, BK=32, 4 LDS buffers, read-ahead frags,
// ONE barrier per K-tile.  ROUND-5 VERIFIED STRUCTURE — do not modify.
// (125.5us GEMM, MfmaUtil 52%, bank conflicts 0, absmax 0.125.
//  x4-unroll variants regressed twice (r6: 265us, r7: 224us) — keep the
//  small 2-tile loop body.)
// Hazard ledger:
//   vmcnt(4) @ tile-t top => all stages except tile t-1's 4 loads
//   complete; tile t+1's buffer (staged in t-2) published before its
//   first read (ph1 of tile t).
//   lgkm: 8 outstanding at tile top; lgkm(4) before m0-3 drains
//   a03(t)/B(t); lgkm(8) before m4-7 drains a47(t). Restage of buffer
//   (t-1)&3 (issued tile t) is separated from its last reads (completed
//   by lgkm(8) in tile t-1) by the tile-t barrier.
// Swizzle (T2): LDS[row][j] = G[row][j ^ ((row>>1)&3)], read chunk
// hi ^ ((lr>>1)&3) -> conflict-free ds_read_b128 (verified: conflicts=0).
// =====================================================================
#define BKg 32
#define TILEB 32768     // (256+256)*32*2 bytes per K-tile buffer
#define ATILEB 16384    // A region size within buffer

__global__ __launch_bounds__(512, 2) void k_gemm256(
    const __bf16* __restrict__ A, const __bf16* __restrict__ B,
    const float* __restrict__ bias, float* __restrict__ C,
    int M, int N, int K)
{
    __shared__ __align__(16) char lds[4 * TILEB];   // 128 KiB
    const int tid = threadIdx.x;
    const int w = tid >> 6, lane = tid & 63;
    const int wm = w >> 2, wn = w & 3;              // 2 (M) x 4 (N) waves
    const int lr = lane & 15, hi = lane >> 4;
    const int NT = K / BKg;

    // bijective XCD-aware block swizzle (m204)
    const int nbx = N / 256;
    const int nwg = nbx * (M / 256);
    const int bid = (int)blockIdx.x;
    const int q = nwg >> 3, r = nwg & 7;
    const int xcd = bid & 7, loc = bid >> 3;
    const int swz = (xcd < r ? xcd * (q + 1) : r * (q + 1) + (xcd - r) * q) + loc;
    const int m0 = (swz / nbx) * 256;
    const int n0 = (swz % nbx) * 256;

    // staging source offsets (pre-swizzled global source, linear LDS dest)
    size_t aOff[2], bOff[2];
#pragma unroll
    for (int L = 0; L < 2; ++L) {
        int c = L * 512 + tid;
        int row = c >> 2, ch = (c & 3) ^ ((c >> 3) & 3);
        aOff[L] = (size_t)(m0 + row) * K + ch * 8;
        bOff[L] = (size_t)(n0 + row) * K + ch * 8;
    }
    int dstOff[2];
#pragma unroll
    for (int L = 0; L < 2; ++L) dstOff[L] = (L * 512 + w * 64) * 16;  // wave-uniform

    // fragment read byte offsets (swizzled read: chunk = hi ^ ((row>>1)&3))
    const int chR = (hi ^ ((lr >> 1) & 3)) * 16;
    const int aRd = (wm * 128 + lr) * 64 + chR;
    const int bRd = ATILEB + (wn * 64 + lr) * 64 + chR;

#define STAGE_A(tt, buf) do {                                              \
    const int kk_ = (tt) * BKg;                                            \
    gload16(A + aOff[0] + kk_, lds + (buf) * TILEB + dstOff[0]);           \
    gload16(A + aOff[1] + kk_, lds + (buf) * TILEB + dstOff[1]);           \
} while (0)
#define STAGE_B(tt, buf) do {                                              \
    const int kk_ = (tt) * BKg;                                            \
    gload16(B + bOff[0] + kk_, lds + (buf) * TILEB + ATILEB + dstOff[0]);  \
    gload16(B + bOff[1] + kk_, lds + (buf) * TILEB + ATILEB + dstOff[1]);  \
} while (0)
#define RD_A(dst, buf, m) dst = *(const bf16x8*)(lds + (buf) * TILEB + aRd + (m) * 1024)
#define RD_B(dst, buf, n) dst = *(const bf16x8*)(lds + (buf) * TILEB + bRd + (n) * 1024)

    f32x4 acc[8][4] = {};
    bf16x8 a03[4], a47[4], b0[4], b1[4];

    // prologue: stage tiles 0,1,2 ; publish tile0 ; read ph0(0) frags
    STAGE_A(0, 0); STAGE_B(0, 0);
    STAGE_A(1, 1); STAGE_B(1, 1);
    STAGE_A(2, 2); STAGE_B(2, 2);
    asm volatile("s_waitcnt vmcnt(8)" ::: "memory");
    __builtin_amdgcn_s_barrier();
    RD_A(a03[0], 0, 0); RD_A(a03[1], 0, 1); RD_A(a03[2], 0, 2); RD_A(a03[3], 0, 3);
    RD_B(b0[0], 0, 0);  RD_B(b0[1], 0, 1);  RD_B(b0[2], 0, 2);  RD_B(b0[3], 0, 3);
    // steady-state invariant: 8 lgkm outstanding at each tile top

#define ITER(t, BCUR, BNXT) do {                                            \
    const int bt = (t) & 3, bt1 = ((t) + 1) & 3, bt3 = ((t) + 3) & 3;       \
    int t3 = (t) + 3; if (t3 >= NT) t3 -= NT;                               \
    /* ---- tile boundary: ONE vmcnt + ONE barrier ---- */                  \
    asm volatile("s_waitcnt vmcnt(4)" ::: "memory");                        \
    __builtin_amdgcn_s_barrier();                                           \
    /* ---- ph0: stage A(t+3); read a47(t); MFMA m0-3(t) ---- */            \
    STAGE_A(t3, bt3);                                                       \
    RD_A(a47[0], bt, 4); RD_A(a47[1], bt, 5);                               \
    RD_A(a47[2], bt, 6); RD_A(a47[3], bt, 7);                               \
    asm volatile("s_waitcnt lgkmcnt(4)" ::: "memory");                      \
    __builtin_amdgcn_sched_barrier(0);                                      \
    __builtin_amdgcn_s_setprio(1);                                          \
    _Pragma("unroll")                                                       \
    for (int m_ = 0; m_ < 4; ++m_)                                          \
        _Pragma("unroll")                                                   \
        for (int n_ = 0; n_ < 4; ++n_)                                      \
            acc[m_][n_] = __builtin_amdgcn_mfma_f32_16x16x32_bf16(          \
                a03[m_], BCUR[n_], acc[m_][n_], 0, 0, 0);                   \
    __builtin_amdgcn_s_setprio(0);                                          \
    __builtin_amdgcn_sched_barrier(0);                                      \
    /* ---- ph1: stage B(t+3); read a03/B(t+1); MFMA m4-7(t) ---- */        \
    STAGE_B(t3, bt3);                                                       \
    if ((t) + 1 < NT) {                                                     \
        RD_A(a03[0], bt1, 0); RD_A(a03[1], bt1, 1);                         \
        RD_A(a03[2], bt1, 2); RD_A(a03[3], bt1, 3);                         \
        RD_B(BNXT[0], bt1, 0); RD_B(BNXT[1], bt1, 1);                       \
        RD_B(BNXT[2], bt1, 2); RD_B(BNXT[3], bt1, 3);                       \
        asm volatile("s_waitcnt lgkmcnt(8)" ::: "memory");                  \
    } else {                                                                \
        asm volatile("s_waitcnt lgkmcnt(0)" ::: "memory");                  \
    }                                                                       \
    __builtin_amdgcn_sched_barrier(0);                                      \
    __builtin_amdgcn_s_setprio(1);                                          \
    _Pragma("unroll")                                                       \
    for (int m_ = 0; m_ < 4; ++m_)                                          \
        _Pragma("unroll")                                                   \
        for (int n_ = 0; n_ < 4; ++n_)                                      \
            acc[m_ + 4][n_] = __builtin_amdgcn_mfma_f32_16x16x32_bf16(      \
                a47[m_], BCUR[n_], acc[m_ + 4][n_], 0, 0, 0);               \
    __builtin_amdgcn_s_setprio(0);                                          \
    __builtin_amdgcn_sched_barrier(0);                                      \
} while (0)

    for (int t = 0; t < NT; t += 2) {
        ITER(t,     b0, b1);
        ITER(t + 1, b1, b0);
    }

    // drain outstanding global_load_lds before block exit
    asm volatile("s_waitcnt vmcnt(0)" ::: "memory");

    // epilogue: C = acc + bias (C/D layout: col=lane&15, row=(lane>>4)*4+reg)
#pragma unroll
    for (int n_ = 0; n_ < 4; ++n_) {
        const int col = n0 + wn * 64 + n_ * 16 + lr;
        const float bv = bias[col];
#pragma unroll
        for (int m_ = 0; m_ < 8; ++m_) {
            const size_t rbase = (size_t)(m0 + wm * 128 + m_ * 16 + hi * 4) * N + col;
            C[rbase]                 = acc[m_][n_][0] + bv;
            C[rbase + N]             = acc[m_][n_][1] + bv;
            C[rbase + 2 * (size_t)N] = acc[m_][n_][2] + bv;
            C[rbase + 3 * (size_t)N] = acc[m_][n_][3] + bv;
        }
    }
#undef ITER
#undef STAGE_A
#undef STAGE_B
#undef RD_A
#undef RD_B
}

// ---- fallback 128x128 GEMM (round-1 verified) ----
template <int MODE>
__global__ __launch_bounds__(256, 2) void k_gemm(
    const __bf16* __restrict__ Ab, const float* __restrict__ Af,
    const __bf16* __restrict__ Bb, const int* __restrict__ Bq,
    const float* __restrict__ scale, const float* __restrict__ zp,
    const float* __restrict__ bias, float* __restrict__ C,
    int M, int N, int K, int NG, int GS)
{
    __shared__ __align__(16) __bf16 As[128 * 32];
    __shared__ __align__(16) __bf16 Bs[128 * 32];

    const int tid  = threadIdx.x;
    const int w    = tid >> 6;
    const int lane = tid & 63;
    const int wm   = w >> 1, wn = w & 1;
    const int m0   = blockIdx.y * 128, n0 = blockIdx.x * 128;
    const int lr   = lane & 15;
    const int lc   = lane >> 4;

    f32x4 acc[4][4] = {};

    for (int kk = 0; kk < K; kk += 32) {
        if constexpr (MODE == 0) {
#pragma unroll
            for (int i = 0; i < 2; i++) {
                int c = i * 256 + tid;
                const __bf16* g = Ab + (size_t)(m0 + (c >> 2)) * K + kk + (c & 3) * 8;
                gload16(g, (char*)As + (i * 256 + w * 64) * 16);
            }
        } else {
            int row = tid >> 1, half = tid & 1;
            const float* g = Af + (size_t)(m0 + row) * K + kk + half * 16;
            float4 f0 = *(const float4*)g;
            float4 f1 = *(const float4*)(g + 4);
            float4 f2 = *(const float4*)(g + 8);
            float4 f3 = *(const float4*)(g + 12);
            bf16x8 v0, v1;
            v0[0] = (__bf16)f0.x; v0[1] = (__bf16)f0.y; v0[2] = (__bf16)f0.z; v0[3] = (__bf16)f0.w;
            v0[4] = (__bf16)f1.x; v0[5] = (__bf16)f1.y; v0[6] = (__bf16)f1.z; v0[7] = (__bf16)f1.w;
            v1[0] = (__bf16)f2.x; v1[1] = (__bf16)f2.y; v1[2] = (__bf16)f2.z; v1[3] = (__bf16)f2.w;
            v1[4] = (__bf16)f3.x; v1[5] = (__bf16)f3.y; v1[6] = (__bf16)f3.z; v1[7] = (__bf16)f3.w;
            *(bf16x8*)(As + row * 32 + half * 16)     = v0;
            *(bf16x8*)(As + row * 32 + half * 16 + 8) = v1;
        }
        if constexpr (MODE <= 1) {
#pragma unroll
            for (int i = 0; i < 2; i++) {
                int c = i * 256 + tid;
                const __bf16* g = Bb + (size_t)(n0 + (c >> 2)) * K + kk + (c & 3) * 8;
                gload16(g, (char*)Bs + (i * 256 + w * 64) * 16);
            }
        } else {
            int row = tid >> 1, half = tid & 1;
            int o = n0 + row;
            int kbase = kk + half * 16;
            int g = kbase / GS;
            float s = scale[(size_t)o * NG + g];
            float z = zp[(size_t)o * NG + g];
            const int* qp = Bq + (size_t)o * K + kbase;
            int4 q0 = *(const int4*)qp;
            int4 q1 = *(const int4*)(qp + 4);
            int4 q2 = *(const int4*)(qp + 8);
            int4 q3 = *(const int4*)(qp + 12);
            bf16x8 v0, v1;
            v0[0] = (__bf16)(((float)q0.x - z) * s); v0[1] = (__bf16)(((float)q0.y - z) * s);
            v0[2] = (__bf16)(((float)q0.z - z) * s); v0[3] = (__bf16)(((float)q0.w - z) * s);
            v0[4] = (__bf16)(((float)q1.x - z) * s); v0[5] = (__bf16)(((float)q1.y - z) * s);
            v0[6] = (__bf16)(((float)q1.z - z) * s); v0[7] = (__bf16)(((float)q1.w - z) * s);
            v1[0] = (__bf16)(((float)q2.x - z) * s); v1[1] = (__bf16)(((float)q2.y - z) * s);
            v1[2] = (__bf16)(((float)q2.z - z) * s); v1[3] = (__bf16)(((float)q2.w - z) * s);
            v1[4] = (__bf16)(((float)q3.x - z) * s); v1[5] = (__bf16)(((float)q3.y - z) * s);
            v1[6] = (__bf16)(((float)q3.z - z) * s); v1[7] = (__bf16)(((float)q3.w - z) * s);
            *(bf16x8*)(Bs + row * 32 + half * 16)     = v0;
            *(bf16x8*)(Bs + row * 32 + half * 16 + 8) = v1;
        }

        __syncthreads();

        bf16x8 af[4], bfm[4];
#pragma unroll
        for (int a = 0; a < 4; a++)
            af[a] = *(const bf16x8*)(As + (wm * 64 + a * 16 + lr) * 32 + lc * 8);
#pragma unroll
        for (int b = 0; b < 4; b++)
            bfm[b] = *(const bf16x8*)(Bs + (wn * 64 + b * 16 + lr) * 32 + lc * 8);
#pragma unroll
        for (int a = 0; a < 4; a++)
#pragma unroll
            for (int b = 0; b < 4; b++)
                acc[a][b] = __builtin_amdgcn_mfma_f32_16x16x32_bf16(af[a], bfm[b], acc[a][b], 0, 0, 0);

        __syncthreads();
    }

#pragma unroll
    for (int b = 0; b < 4; b++) {
        int col = n0 + wn * 64 + b * 16 + lr;
        float bv = bias[col];
#pragma unroll
        for (int a = 0; a < 4; a++) {
            int rbase = m0 + wm * 64 + a * 16 + lc * 4;
#pragma unroll
            for (int r = 0; r < 4; r++)
                C[(size_t)(rbase + r) * N + col] = acc[a][b][r] + bv;
        }
    }
}

extern "C" void kernel_launch(void* const* d_in, const int* in_sizes, int n_in,
                              void* d_out, int out_size, void* d_ws, size_t ws_size,
                              hipStream_t stream) {
    const float* x     = (const float*)d_in[0];
    const int*   wq    = (const int*)d_in[1];
    const float* scale = (const float*)d_in[2];
    const float* zp    = (const float*)d_in[3];
    const float* bias  = (const float*)d_in[4];
    float* out = (float*)d_out;

    const int    N  = in_sizes[4];
    const long   K  = in_sizes[1] / N;
    const long   M  = in_sizes[0] / K;
    const int    NG = in_sizes[2] / N;
    const int    GS = (int)(K / NG);

    const size_t wbytes = (size_t)N * K * sizeof(__bf16);
    const size_t xbytes = (size_t)M * K * sizeof(__bf16);

    char* ws = (char*)d_ws;
    __bf16* wb = (__bf16*)ws;
    __bf16* xb = (__bf16*)(ws + wbytes);

    const bool big = (M % 256 == 0) && (N % 256 == 0) && (K % 64 == 0) && (K / 32 >= 4);

    if (ws_size >= wbytes + xbytes) {
        size_t nx = (size_t)M * K;
        size_t nw = (size_t)N * K;
        unsigned nxb = (unsigned)((nx / 8 + 255) / 256);
        unsigned nwb = (unsigned)((nw / 8 + 255) / 256);
        k_prep<<<nxb + nwb, 256, 0, stream>>>(x, xb, nx, wq, scale, zp, wb,
                                              (int)K, GS, NG, (int)nxb);
        if (big) {
            unsigned nwg = (unsigned)((M / 256) * (N / 256));
            k_gemm256<<<nwg, 512, 0, stream>>>(xb, wb, bias, out, (int)M, N, (int)K);
        } else {
            dim3 grid((unsigned)(N / 128), (unsigned)(M / 128)), blk(256);
            k_gemm<0><<<grid, blk, 0, stream>>>(xb, nullptr, wb, nullptr, scale, zp, bias, out,
                                                (int)M, N, (int)K, NG, GS);
        }
    } else if (ws_size >= wbytes) {
        size_t nw = (size_t)N * K;
        dim3 grid((unsigned)(N / 128), (unsigned)(M / 128)), blk(256);
        k_dequant_w<<<(unsigned)((nw / 8 + 255) / 256), 256, 0, stream>>>(wq, scale, zp, wb, (int)K, GS, NG);
        k_gemm<1><<<grid, blk, 0, stream>>>(nullptr, x, wb, nullptr, scale, zp, bias, out,
                                            (int)M, N, (int)K, NG, GS);
    } else {
        dim3 grid((unsigned)(N / 128), (unsigned)(M / 128)), blk(256);
        k_gemm<2><<<grid, blk, 0, stream>>>(nullptr, x, nullptr, wq, scale, zp, bias, out,
                                            (int)M, N, (int)K, NG, GS);
    }
}